// Round 2
// baseline (185.517 us; speedup 1.0000x reference)
//
#include <hip/hip_runtime.h>
#include <hip/hip_bf16.h>

// out[b,o,hw] = sum_c W[o,c] * relu(x[b,c,hw]*scale[c] + shift[c])
// B=256, Cin=2112, Cout=192, HW=49, fp32 in HBM, bf16 MFMA internally.
//
// R9 = R8 fused kernel, restructured for latency hiding:
//  * grid 512 = (b, Cout-half): 2 independent 4-wave blocks per CU
//    (R8 had ONE 8-wave barrier group per CU -> every barrier stalled the
//    whole CU). x[b] is read by 2 co-resident blocks; 2nd read is L3-hit.
//  * main loop ROLLED into 33 pair-steps (was fully unrolled: ~60 KB body
//    thrashed the 32 KB L1I). Parity rings are STATIC by construction
//    (arE/arO, xvA/xvB named slots) -> no dynamic-index scratch spill.
//  * same single-s_barrier-per-step scheme, same LDS swizzle as R8.

#define CIN    2112
#define COUT   192
#define HWS    49
#define BK     32
#define NSTEP  (CIN / BK)     // 66
#define EPSV   1e-5f
#define SLAB   (BK * HWS)     // 1568 elements per (b,ks) slab

typedef __bf16 bf16;
typedef __attribute__((ext_vector_type(8))) __bf16 bf16x8;
typedef __attribute__((ext_vector_type(4))) float  f32x4;

// ---------- kernel 1: W fp32 -> bf16 in A-fragment order (unchanged) ----------
__global__ __launch_bounds__(256)
void w_repack_kernel(const float* __restrict__ W, bf16* __restrict__ Wb) {
    const int t = blockIdx.x * 256 + threadIdx.x;       // 66*12*64 = 50688
    if (t >= NSTEP * 12 * 64) return;
    const int lane = t & 63;
    const int gmt  = (t >> 6) % 12;
    const int ks   = t / (12 * 64);
    const int row  = gmt * 16 + (lane & 15);
    const int k    = ks * BK + (lane >> 4) * 8;
    const float* src = W + (size_t)row * CIN + k;
    f32x4 a = *(const f32x4*)src;
    f32x4 c = *(const f32x4*)(src + 4);
    bf16x8 o;
    #pragma unroll
    for (int j = 0; j < 4; j++) { o[j] = (bf16)a[j]; o[j + 4] = (bf16)c[j]; }
    *(bf16x8*)(Wb + (size_t)t * 8) = o;
}

// ---------- kernel 2: fused BN+ReLU+transpose-pack+GEMM ----------
__global__ __launch_bounds__(256, 2)
void fused_kernel(const float* __restrict__ x,
                  const float* __restrict__ gamma,
                  const float* __restrict__ beta,
                  const float* __restrict__ rmean,
                  const float* __restrict__ rvar,
                  const bf16* __restrict__ Wb,
                  float* __restrict__ out)
{
    __shared__ float2 ss[CIN + 2];                   // BN scale/shift (+pad)
    __shared__ __align__(16) bf16 bt[2][SLAB];       // double-buffered B tile

    const int tid = threadIdx.x;
    const int b   = blockIdx.x & 255;                // image
    const int mh  = blockIdx.x >> 8;                 // Cout half: rows mh*96..

    // BN params -> LDS
    for (int c = tid; c < CIN; c += 256) {
        float inv = rsqrtf(rvar[c] + EPSV);
        float s   = gamma[c] * inv;
        ss[c] = make_float2(s, beta[c] - rmean[c] * s);
    }
    if (tid < 2) ss[CIN + tid] = make_float2(0.f, 0.f);

    // ---- staging role: threads 0..195 own 8 consecutive floats of the slab
    const bool act = tid < (SLAB / 8);               // 196
    const int fb  = tid * 8;
    const int cl0 = fb / HWS;                        // channel-in-slab 0..31
    const int hw0 = fb - cl0 * HWS;
    const int jw  = (hw0 + 8 <= HWS) ? 8 : (HWS - hw0);   // elems in cl0
    int addrs[8];
    #pragma unroll
    for (int j = 0; j < 8; j++) {
        int hw = hw0 + j, cl = cl0;
        if (hw >= HWS) { hw -= HWS; cl += 1; }
        const int rot = ((cl >> 3) + (hw >> 2)) & 3;      // bank swizzle
        addrs[j] = hw * BK + rot * 8 + (cl & 7);
    }
    const float* xs = x + (size_t)b * (CIN * HWS) + fb;

    // ---- compute role: 4 waves = 2 M-groups x 2 N-groups
    const int lane = tid & 63;
    const int wv   = tid >> 6;
    const int mg   = wv & 1;          // 48 Cout rows within the half
    const int ng   = wv >> 1;         // 32 hw cols
    const int l15  = lane & 15;
    const int q    = lane >> 4;

    const int hwc0 = ng * 32 + l15;               // <= 47, always valid
    int hwc1 = ng * 32 + 16 + l15;
    if (hwc1 > 48) hwc1 = 48;                     // dup col 48 (ng=1 tail)
    const int bad0 = hwc0 * BK + ((q + (hwc0 >> 2)) & 3) * 8;
    const int bad1 = hwc1 * BK + ((q + (hwc1 >> 2)) & 3) * 8;

    const int gmtBase = mh * 6 + mg * 3;
    const bf16* apL = Wb + (size_t)gmtBase * 512 + (size_t)lane * 8;

    f32x4 acc[3][2];
    #pragma unroll
    for (int mt = 0; mt < 3; mt++) { acc[mt][0] = (f32x4)(0.f); acc[mt][1] = (f32x4)(0.f); }

    // prologue: slab0 temp + 2-deep parity-slotted x prefetch, A ring preload
    f32x4 t0 = (f32x4)(0.f), t1 = (f32x4)(0.f);
    f32x4 xvA0 = (f32x4)(0.f), xvA1 = (f32x4)(0.f);
    f32x4 xvB0 = (f32x4)(0.f), xvB1 = (f32x4)(0.f);
    if (act) {
        t0   = *(const f32x4*)(xs);
        t1   = *(const f32x4*)(xs + 4);
        xvA0 = *(const f32x4*)(xs + SLAB);          // slab 1 (even steps slot)
        xvA1 = *(const f32x4*)(xs + SLAB + 4);
        xvB0 = *(const f32x4*)(xs + 2 * SLAB);      // slab 2 (odd steps slot)
        xvB1 = *(const f32x4*)(xs + 2 * SLAB + 4);
    }
    bf16x8 arE[3], arO[3];
    #pragma unroll
    for (int mt = 0; mt < 3; mt++) {
        arE[mt] = *(const bf16x8*)(apL + (size_t)(mt * 512));            // ks=0
        arO[mt] = *(const bf16x8*)(apL + (size_t)(6144 + mt * 512));     // ks=1
    }

    __syncthreads();   // ss ready

    // stage slab 0 into bt[0]
    if (act) {
        const float2 s0 = ss[cl0];
        const float2 s1 = ss[cl0 + 1];
        #pragma unroll
        for (int j = 0; j < 8; j++) {
            const float xj = (j < 4) ? t0[j] : t1[j - 4];
            const float sc = (j >= jw) ? s1.x : s0.x;
            const float sh = (j >= jw) ? s1.y : s0.y;
            bt[0][addrs[j]] = (bf16)fmaxf(fmaf(xj, sc, sh), 0.f);
        }
    }
    asm volatile("s_waitcnt lgkmcnt(0)" ::: "memory");
    __builtin_amdgcn_s_barrier();
    __builtin_amdgcn_sched_barrier(0);

    // one step: read bt[p]; stage slab ks+1 -> bt[p^1]; load slab ks+3 into
    // this parity's x slot; barrier; MFMA with ar; reload ar <- A[ks+2].
    auto STEP = [&](int p, int ks, f32x4& xv0, f32x4& xv1, bf16x8 (&ar)[3]) {
        const bf16x8 b0 = *(const bf16x8*)&bt[p][bad0];
        const bf16x8 b1 = *(const bf16x8*)&bt[p][bad1];
        if (act) {
            int sl = ks + 1; if (sl > NSTEP - 1) sl = NSTEP - 1;   // tail-safe
            const int cb = sl * BK;
            const float2 s0 = ss[cb + cl0];
            const float2 s1 = ss[cb + cl0 + 1];
            #pragma unroll
            for (int j = 0; j < 8; j++) {
                const float xj = (j < 4) ? xv0[j] : xv1[j - 4];
                const float sc = (j >= jw) ? s1.x : s0.x;
                const float sh = (j >= jw) ? s1.y : s0.y;
                bt[p ^ 1][addrs[j]] = (bf16)fmaxf(fmaf(xj, sc, sh), 0.f);
            }
            int ln = ks + 3; if (ln > NSTEP - 1) ln = NSTEP - 1;
            xv0 = *(const f32x4*)(xs + (size_t)ln * SLAB);
            xv1 = *(const f32x4*)(xs + (size_t)ln * SLAB + 4);
        }
        asm volatile("s_waitcnt lgkmcnt(0)" ::: "memory");
        __builtin_amdgcn_s_barrier();
        __builtin_amdgcn_sched_barrier(0);
        #pragma unroll
        for (int mt = 0; mt < 3; mt++) {
            acc[mt][0] = __builtin_amdgcn_mfma_f32_16x16x32_bf16(ar[mt], b0, acc[mt][0], 0, 0, 0);
            acc[mt][1] = __builtin_amdgcn_mfma_f32_16x16x32_bf16(ar[mt], b1, acc[mt][1], 0, 0, 0);
        }
        int kf = ks + 2; if (kf > NSTEP - 1) kf = NSTEP - 1;
        #pragma unroll
        for (int mt = 0; mt < 3; mt++)
            ar[mt] = *(const bf16x8*)(apL + (size_t)kf * 6144 + (size_t)(mt * 512));
    };

    // ROLLED main loop: 33 pair-steps, ~1.5 KB body (I-cache resident),
    // all ring slots static.
    #pragma unroll 1
    for (int it = 0; it < NSTEP / 2; ++it) {
        const int ks = it * 2;
        STEP(0, ks,     xvA0, xvA1, arE);
        STEP(1, ks + 1, xvB0, xvB1, arO);
    }

    // epilogue: C/D layout col=l15 -> hw, row=q*4+r. Disjoint stores.
    float* ob = out + (size_t)b * (COUT * HWS);
    const int hw1 = ng * 32 + 16 + l15;            // unclamped for predicate
    #pragma unroll
    for (int mt = 0; mt < 3; mt++) {
        const int row0 = mh * 96 + mg * 48 + mt * 16 + q * 4;
        #pragma unroll
        for (int r = 0; r < 4; r++)
            ob[(size_t)(row0 + r) * HWS + hwc0] = acc[mt][0][r];
        if (hw1 < HWS) {
            #pragma unroll
            for (int r = 0; r < 4; r++)
                ob[(size_t)(row0 + r) * HWS + hw1] = acc[mt][1][r];
        }
    }
}

extern "C" void kernel_launch(void* const* d_in, const int* in_sizes, int n_in,
                              void* d_out, int out_size, void* d_ws, size_t ws_size,
                              hipStream_t stream) {
    const float* x     = (const float*)d_in[0];
    const float* gamma = (const float*)d_in[1];
    const float* beta  = (const float*)d_in[2];
    const float* rmean = (const float*)d_in[3];
    const float* rvar  = (const float*)d_in[4];
    const float* W     = (const float*)d_in[5];
    float* out = (float*)d_out;

    bf16* Wb = (bf16*)d_ws;                        // 811,008 B, L2-resident

    w_repack_kernel<<<dim3(198), dim3(256), 0, stream>>>(W, Wb);
    fused_kernel<<<dim3(512), dim3(256), 0, stream>>>(
        x, gamma, beta, rmean, rvar, Wb, out);
}

// Round 4
// 177.923 us; speedup vs baseline: 1.0427x; 1.0427x over previous
//
#include <hip/hip_runtime.h>
#include <hip/hip_bf16.h>

// out[b,o,hw] = sum_c W[o,c] * relu(x[b,c,hw]*scale[c] + shift[c])
// B=256, Cin=2112, Cout=192, HW=49, fp32 in HBM, bf16 MFMA internally.
//
// R11 = R10 resubmitted (round-3 bench died to a container-acquisition
// flake before running; kernel audited for hang/race/OOB -- none found).
// BK 32 -> 192 (2112 = 192*11): 11 barrier-separated K-steps instead of
// 66. R8/R9 both measured ~2360 cy per K-step regardless of wave grouping
// -> the per-step {stage scatter + lgkmcnt(0) + s_barrier} chain was the
// invariant cost, amortized over only 6 MFMAs. Now each step is 6
// unrolled sub-phases {2 ds_read_b128, stage one 32-ch sub-slab of the
// NEXT slab, 6 MFMA, 3 A-frag reloads, 1 x prefetch}, ONE
// lgkmcnt(0)+s_barrier per step, no vmcnt drain ever. Rings (arE/arO,
// xv[6]) static via full sub-phase unroll; outer 11-step loop stays
// rolled (I-cache resident). Grid 256 (1 block/image, 8 waves): x read
// from HBM exactly once.

#define CIN    2112
#define COUT   192
#define HWS    49
#define BK     32                  // channels per sub-slab (MFMA K granule)
#define NSUB   6                   // sub-slabs per step
#define BKS    (BK * NSUB)         // 192 channels per barrier step
#define NSTEP  (CIN / BKS)         // 11
#define NK32   (CIN / BK)          // 66 (A-fragment granule count)
#define EPSV   1e-5f
#define SSLAB  (BK * HWS)          // 1568 elems per 32-ch sub-slab
#define SLAB   (BKS * HWS)         // 9408 elems per step tile

typedef __bf16 bf16;
typedef __attribute__((ext_vector_type(8))) __bf16 bf16x8;
typedef __attribute__((ext_vector_type(4))) float  f32x4;

// ---------- kernel 1: W fp32 -> bf16 in A-fragment order (unchanged) ----------
__global__ __launch_bounds__(256)
void w_repack_kernel(const float* __restrict__ W, bf16* __restrict__ Wb) {
    const int t = blockIdx.x * 256 + threadIdx.x;       // 66*12*64 = 50688
    if (t >= NK32 * 12 * 64) return;
    const int lane = t & 63;
    const int gmt  = (t >> 6) % 12;
    const int ks   = t / (12 * 64);
    const int row  = gmt * 16 + (lane & 15);
    const int k    = ks * BK + (lane >> 4) * 8;
    const float* src = W + (size_t)row * CIN + k;
    f32x4 a = *(const f32x4*)src;
    f32x4 c = *(const f32x4*)(src + 4);
    bf16x8 o;
    #pragma unroll
    for (int j = 0; j < 4; j++) { o[j] = (bf16)a[j]; o[j + 4] = (bf16)c[j]; }
    *(bf16x8*)(Wb + (size_t)t * 8) = o;
}

// ---------- kernel 2: fused BN+ReLU+transpose-pack+GEMM ----------
__global__ __launch_bounds__(512, 2)
void fused_kernel(const float* __restrict__ x,
                  const float* __restrict__ gamma,
                  const float* __restrict__ beta,
                  const float* __restrict__ rmean,
                  const float* __restrict__ rvar,
                  const bf16* __restrict__ Wb,
                  float* __restrict__ out)
{
    __shared__ float2 ss[CIN + 2];                   // BN scale/shift (+pad)
    __shared__ __align__(16) bf16 bt[2][SLAB];       // double-buffered 192x49

    const int tid = threadIdx.x;
    const int b   = blockIdx.x;

    // BN params -> LDS
    for (int c = tid; c < CIN; c += 512) {
        float inv = rsqrtf(rvar[c] + EPSV);
        float s   = gamma[c] * inv;
        ss[c] = make_float2(s, beta[c] - rmean[c] * s);
    }
    if (tid < 2) ss[CIN + tid] = make_float2(0.f, 0.f);

    // ---- staging role: threads 0..391 own 4 consecutive floats of a sub-slab
    const bool act = tid < (SSLAB / 4);              // 392
    const int fb  = tid * 4;
    const int cl0 = fb / HWS;                        // channel-in-sub-slab 0..31
    const int hw0 = fb - cl0 * HWS;
    const int jw  = (hw0 + 4 <= HWS) ? 4 : (HWS - hw0);
    int addrs[4];
    #pragma unroll
    for (int j = 0; j < 4; j++) {
        int hw = hw0 + j, cl = cl0;
        if (hw >= HWS) { hw -= HWS; cl += 1; }
        const int rot = ((cl >> 3) + (hw >> 2)) & 3;      // bank swizzle
        addrs[j] = hw * BK + rot * 8 + (cl & 7);
    }
    const float* xs = x + (size_t)b * (CIN * HWS) + fb;

    // ---- compute role: 8 waves = 4 M-groups x 2 N-groups
    const int lane = tid & 63;
    const int wv   = tid >> 6;
    const int mg   = wv & 3;          // 48 Cout rows
    const int ng   = wv >> 2;         // 32 hw cols
    const int l15  = lane & 15;
    const int q    = lane >> 4;

    const int hwc0 = ng * 32 + l15;               // <= 47, always valid
    int hwc1 = ng * 32 + 16 + l15;
    if (hwc1 > 48) hwc1 = 48;                     // dup col 48 (ng=1 tail)
    const int bad0 = hwc0 * BK + ((q + (hwc0 >> 2)) & 3) * 8;
    const int bad1 = hwc1 * BK + ((q + (hwc1 >> 2)) & 3) * 8;

    const bf16* apL = Wb + (size_t)(mg * 3) * 512 + (size_t)lane * 8;

    f32x4 acc[3][2];
    #pragma unroll
    for (int mt = 0; mt < 3; mt++) { acc[mt][0] = (f32x4)(0.f); acc[mt][1] = (f32x4)(0.f); }

    f32x4 xv[NSUB];                                  // next-slab prefetch regs
    #pragma unroll
    for (int i = 0; i < NSUB; i++) xv[i] = (f32x4)(0.f);

    // A-frag parity ring, preloaded ks32 = 0,1
    bf16x8 arE[3], arO[3];
    #pragma unroll
    for (int mt = 0; mt < 3; mt++) {
        arE[mt] = *(const bf16x8*)(apL + (size_t)(mt * 512));
        arO[mt] = *(const bf16x8*)(apL + (size_t)(6144 + mt * 512));
    }

    __syncthreads();   // ss ready

    // prologue: stage slab 0 (6 sub-slabs) into bt[0], then prefetch slab 1
    if (act) {
        #pragma unroll
        for (int i = 0; i < NSUB; i++) {
            const f32x4 v = *(const f32x4*)(xs + (size_t)i * SSLAB);
            const int cb = i * BK;
            const float2 s0 = ss[cb + cl0];
            const float2 s1 = ss[cb + cl0 + 1];
            #pragma unroll
            for (int j = 0; j < 4; j++) {
                const float sc = (j >= jw) ? s1.x : s0.x;
                const float sh = (j >= jw) ? s1.y : s0.y;
                bt[0][i * SSLAB + addrs[j]] = (bf16)fmaxf(fmaf(v[j], sc, sh), 0.f);
            }
        }
        #pragma unroll
        for (int i = 0; i < NSUB; i++)
            xv[i] = *(const f32x4*)(xs + (size_t)(NSUB + i) * SSLAB);
    }
    asm volatile("s_waitcnt lgkmcnt(0)" ::: "memory");
    __builtin_amdgcn_s_barrier();
    __builtin_amdgcn_sched_barrier(0);

    // main loop: 11 steps, ONE barrier per step. Step ks reads bt[ks&1],
    // stages slab ks+1 into bt[(ks&1)^1]. 6 sub-phases fully unrolled.
    #pragma unroll 1
    for (int ks = 0; ks < NSTEP; ++ks) {
        const int p = ks & 1;
        const bf16* btp = &bt[p][0];
        bf16* btn = &bt[p ^ 1][0];
        const bool stg = act && (ks < NSTEP - 1);
        const int ks32 = ks * NSUB;                  // global 32-ch index

        #pragma unroll
        for (int kk = 0; kk < NSUB; ++kk) {          // static ring indices
            const bf16x8 b0 = *(const bf16x8*)&btp[kk * SSLAB + bad0];
            const bf16x8 b1 = *(const bf16x8*)&btp[kk * SSLAB + bad1];

            if (stg) {                               // stage sub-slab kk of slab ks+1
                const int cb = (ks + 1) * BKS + kk * BK;
                const float2 s0 = ss[cb + cl0];
                const float2 s1 = ss[cb + cl0 + 1];
                const f32x4 v = xv[kk];
                #pragma unroll
                for (int j = 0; j < 4; j++) {
                    const float sc = (j >= jw) ? s1.x : s0.x;
                    const float sh = (j >= jw) ? s1.y : s0.y;
                    btn[kk * SSLAB + addrs[j]] = (bf16)fmaxf(fmaf(v[j], sc, sh), 0.f);
                }
                // prefetch sub-slab kk of slab ks+2 (clamped at tail)
                int ln = ks + 2; if (ln > NSTEP - 1) ln = NSTEP - 1;
                xv[kk] = *(const f32x4*)(xs + ((size_t)ln * NSUB + kk) * SSLAB);
            }

            bf16x8* ar = (kk & 1) ? arO : arE;
            #pragma unroll
            for (int mt = 0; mt < 3; mt++) {
                acc[mt][0] = __builtin_amdgcn_mfma_f32_16x16x32_bf16(ar[mt], b0, acc[mt][0], 0, 0, 0);
                acc[mt][1] = __builtin_amdgcn_mfma_f32_16x16x32_bf16(ar[mt], b1, acc[mt][1], 0, 0, 0);
            }
            // reload this parity's A-frags for ks32+kk+2 (clamped)
            int tk = ks32 + kk + 2; if (tk > NK32 - 1) tk = NK32 - 1;
            #pragma unroll
            for (int mt = 0; mt < 3; mt++)
                ar[mt] = *(const bf16x8*)(apL + (size_t)tk * 6144 + (size_t)(mt * 512));
        }

        asm volatile("s_waitcnt lgkmcnt(0)" ::: "memory");
        __builtin_amdgcn_s_barrier();
        __builtin_amdgcn_sched_barrier(0);
    }

    // epilogue: C/D layout col=l15 -> hw, row=q*4+r. Disjoint stores.
    float* ob = out + (size_t)b * (COUT * HWS);
    const int hw1 = ng * 32 + 16 + l15;            // unclamped for predicate
    #pragma unroll
    for (int mt = 0; mt < 3; mt++) {
        const int row0 = mg * 48 + mt * 16 + q * 4;
        #pragma unroll
        for (int r = 0; r < 4; r++)
            ob[(size_t)(row0 + r) * HWS + hwc0] = acc[mt][0][r];
        if (hw1 < HWS) {
            #pragma unroll
            for (int r = 0; r < 4; r++)
                ob[(size_t)(row0 + r) * HWS + hw1] = acc[mt][1][r];
        }
    }
}

extern "C" void kernel_launch(void* const* d_in, const int* in_sizes, int n_in,
                              void* d_out, int out_size, void* d_ws, size_t ws_size,
                              hipStream_t stream) {
    const float* x     = (const float*)d_in[0];
    const float* gamma = (const float*)d_in[1];
    const float* beta  = (const float*)d_in[2];
    const float* rmean = (const float*)d_in[3];
    const float* rvar  = (const float*)d_in[4];
    const float* W     = (const float*)d_in[5];
    float* out = (float*)d_out;

    bf16* Wb = (bf16*)d_ws;                        // 811,008 B, L2-resident

    w_repack_kernel<<<dim3(198), dim3(256), 0, stream>>>(W, Wb);
    fused_kernel<<<dim3(256), dim3(512), 0, stream>>>(
        x, gamma, beta, rmean, rvar, Wb, out);
}